// Round 10
// baseline (39.234 us; speedup 1.0000x reference)
//
#include <hip/hip_runtime.h>
#include <hip/hip_bf16.h>

#define N_TOT 2048
#define M_DIM 64
#define O_DIM 128
#define NT 32   // neurons per block -> w1 n-runs = 128 B (2 HBM bursts/row-activation)
#define OC 64   // o-columns per block -> out runs 256 B

typedef __bf16 bf16x8 __attribute__((ext_vector_type(8)));
typedef float f32x4 __attribute__((ext_vector_type(4)));

// Grid 256 = 64 ngroups x 2 o-halves x 2 b-halves; block 512 thr (8 waves).
// Two k-phases of 32 (acc persistent): per phase stage w1[m32][o64][n32]
// (128 KiB LDS, [nn32][ol64][k32] bf16, no swizzle - LDS proven off critical
// path) then 32 MFMAs/wave. The ONLY intended change vs r9: w1's HBM access
// grain 64B->128B n-runs (DRAM row-activation theory). w1/x re-reads (x2)
// are same-XCD L2 hits via adjacent dispatch of the 4 sibling blocks.
__global__ __launch_bounds__(512, 2) void superlinear_mfma(
    const float* __restrict__ x, const float* __restrict__ w1,
    const float* __restrict__ b1, float* __restrict__ out)
{
    __shared__ unsigned char wlds[NT * OC * 32 * 2];   // 128 KiB

    const int tid  = threadIdx.x;
    const int lane = tid & 63;
    const int wave = tid >> 6;   // 0..7; wave owns neurons wave*4 .. +3

    // XCD swizzle: XCD k hosts swz [32k,32k+32) = 8 complete ngroups with all
    // 4 siblings (2 oh x 2 bh) adjacent -> shared w1/x slices hit same L2.
    const int bid = blockIdx.x;
    const int swz = (bid & 7) * 32 + (bid >> 3);
    const int ng  = swz >> 2;
    const int oh  = (swz >> 1) & 1;
    const int bh  = swz & 1;
    const int n0  = ng * NT;
    const int o0  = oh * OC;
    const int b0  = bh * 32;

    const int col = lane & 15;   // o-local / b-row-local / D-col
    const int kg  = lane >> 4;   // k-group (8 elements)

    // staging decomposition: thread -> (n-float4 n8, o-local ol), loops m
    const int n8 = tid & 7;            // float4 index along the 32-n extent
    const int ol = (tid >> 3) & 63;    // o within block

    const size_t MSTR = (size_t)O_DIM * N_TOT;   // w1 m-stride (floats)

    // ---- acc init = bias (C-in of first MFMA chain) ----
    f32x4 acc[4][2][4];   // [n2][bt][ot]
    #pragma unroll
    for (int n2 = 0; n2 < 4; ++n2) {
        int n = n0 + wave * 4 + n2;
        #pragma unroll
        for (int ot = 0; ot < 4; ++ot) {
            float bvv = b1[(size_t)n * O_DIM + o0 + ot * 16 + col];
            #pragma unroll
            for (int bt = 0; bt < 2; ++bt) {
                acc[n2][bt][ot][0] = bvv; acc[n2][bt][ot][1] = bvv;
                acc[n2][bt][ot][2] = bvv; acc[n2][bt][ot][3] = bvv;
            }
        }
    }

    // ---- two k-phases of 32 ----
    #pragma unroll
    for (int p = 0; p < 2; ++p) {
        // x fragments for this phase (independent of LDS; issued first)
        float4 xr[4][2][2];   // [n2][bt][h]
        #pragma unroll
        for (int n2 = 0; n2 < 4; ++n2)
            #pragma unroll
            for (int bt = 0; bt < 2; ++bt) {
                const float* xp = x
                    + ((size_t)(b0 + bt * 16 + col) * N_TOT + (n0 + wave * 4 + n2)) * M_DIM
                    + p * 32 + kg * 8;
                xr[n2][bt][0] = *(const float4*)xp;
                xr[n2][bt][1] = *(const float4*)(xp + 4);
            }

        // stage w1[p*32..+32][o0..+64][n0..+32] -> LDS [nn][ol][k32]
        #pragma unroll
        for (int sb = 0; sb < 4; ++sb) {
            float4 r[8];
            const float* gp = w1 + ((size_t)(p * 32 + sb * 8) * O_DIM + (o0 + ol)) * N_TOT
                                 + n0 + n8 * 4;
            #pragma unroll
            for (int mm = 0; mm < 8; ++mm)
                r[mm] = *(const float4*)(gp + (size_t)mm * MSTR);
            #pragma unroll
            for (int j = 0; j < 4; ++j) {
                int nn = n8 * 4 + j;
                bf16x8 v;
                #pragma unroll
                for (int mm = 0; mm < 8; ++mm)
                    v[mm] = (__bf16)(((const float*)&r[mm])[j]);
                *(bf16x8*)(wlds + (unsigned)(nn * 4096 + ol * 64 + sb * 16)) = v;
            }
        }

        // convert x while staging writes drain
        bf16x8 af[4][2];
        #pragma unroll
        for (int n2 = 0; n2 < 4; ++n2)
            #pragma unroll
            for (int bt = 0; bt < 2; ++bt) {
                const float* lp = (const float*)&xr[n2][bt][0];
                const float* hp = (const float*)&xr[n2][bt][1];
                bf16x8 v;
                #pragma unroll
                for (int t = 0; t < 4; ++t) {
                    v[t]     = (__bf16)lp[t];
                    v[4 + t] = (__bf16)hp[t];
                }
                af[n2][bt] = v;
            }

        __syncthreads();

        // consume: per wave 4 neurons x 4 o-tiles x 2 b-tiles = 32 MFMAs
        #pragma unroll
        for (int n2 = 0; n2 < 4; ++n2) {
            int nn = wave * 4 + n2;
            #pragma unroll
            for (int ot = 0; ot < 4; ++ot) {
                bf16x8 bfrag = *(const bf16x8*)(wlds
                    + (unsigned)(nn * 4096 + (ot * 16 + col) * 64 + kg * 16));
                #pragma unroll
                for (int bt = 0; bt < 2; ++bt)
                    acc[n2][bt][ot] = __builtin_amdgcn_mfma_f32_16x16x32_bf16(
                        af[n2][bt], bfrag, acc[n2][bt][ot], 0, 0, 0);
            }
        }

        if (p == 0) __syncthreads();   // LDS rewritten next phase
    }

    // ---- stores: 256 B o-run per (b,n) row, 16-lane x 64 B segments ----
    #pragma unroll
    for (int n2 = 0; n2 < 4; ++n2) {
        int n = n0 + wave * 4 + n2;
        #pragma unroll
        for (int bt = 0; bt < 2; ++bt)
            #pragma unroll
            for (int j = 0; j < 4; ++j) {
                int b = b0 + bt * 16 + kg * 4 + j;
                float* op = out + ((size_t)b * N_TOT + n) * O_DIM + o0 + col;
                op[0]  = acc[n2][bt][0][j];
                op[16] = acc[n2][bt][1][j];
                op[32] = acc[n2][bt][2][j];
                op[48] = acc[n2][bt][3][j];
            }
    }
}

extern "C" void kernel_launch(void* const* d_in, const int* in_sizes, int n_in,
                              void* d_out, int out_size, void* d_ws, size_t ws_size,
                              hipStream_t stream) {
    const float* x  = (const float*)d_in[0];
    const float* w1 = (const float*)d_in[1];
    const float* b1 = (const float*)d_in[2];
    float* out = (float*)d_out;
    superlinear_mfma<<<dim3(256), dim3(512), 0, stream>>>(x, w1, b1, out);
}

// Round 11
// 35.435 us; speedup vs baseline: 1.1072x; 1.1072x over previous
//
#include <hip/hip_runtime.h>
#include <hip/hip_bf16.h>

#define N_TOT 2048
#define M_DIM 64
#define O_DIM 128
#define NT 8   // neurons per block

typedef __bf16 bf16x8 __attribute__((ext_vector_type(8)));
typedef float f32x4 __attribute__((ext_vector_type(4)));

// TERMINAL KERNEL (best measured: 35.4 us, r7).
// Grid 256 x 512 thr (1 block/CU, wave w = neuron n0+w, full 64 b-rows).
// W staged in 4 chunks of 32 o-columns (32 KiB), triple-buffered: the
// ds_write of chunk c+1 waits on global loads issued a full iteration
// earlier (latency covered), while chunk c+2's loads go into flight.
// Stores emit each (b,n)-row's full 128 B o-pair back-to-back (clean HBM
// write-back, WRITE_SIZE == 65.5 MB exactly). Barriers are lgkm-only.
// Structural ceiling: w1[m,o,n] n-innermost forces a 64B-line gather at
// 8KB stride for 67 of 165 compulsory MB; measured 4.8 TB/s fabric-side
// (HBM 3.4 + L3-served) == mixed-stream ceiling for this access pattern.
__global__ __launch_bounds__(512, 2) void superlinear_mfma(
    const float* __restrict__ x, const float* __restrict__ w1,
    const float* __restrict__ b1, float* __restrict__ out)
{
    __shared__ unsigned char wlds[3 * NT * 32 * M_DIM * 2];  // 3 x 32 KiB

    const int tid  = threadIdx.x;
    const int lane = tid & 63;
    const int wave = tid >> 6;   // 0..7 = neuron within block (compute role)

    // XCD-aware swizzle: 256 blocks / 8 XCDs -> 32 consecutive nblk per XCD
    const int bid  = blockIdx.x;
    const int nblk = (bid & 7) * 32 + (bid >> 3);
    const int n0   = nblk * NT;
    const int n    = n0 + wave;

    const int col = lane & 15;   // o (and b-row) index within 16-tile
    const int kg  = lane >> 4;   // k-group (8 bf16)

    // staging decomposition: thread -> (n-half, o-local in chunk, 8 m-rows)
    const int half = tid & 1;
    const int ol   = (tid >> 1) & 31;
    const int mseg = tid >> 6;            // m-rows mseg*8 .. +7

    const size_t MSTR = (size_t)O_DIM * N_TOT;   // w1 m-stride (floats)

    auto stage_issue = [&](int c, float4* r) {
        const float* gp = w1 + ((size_t)(mseg * 8) * O_DIM + (c * 32 + ol)) * N_TOT
                             + n0 + half * 4;
        #pragma unroll
        for (int mm = 0; mm < 8; ++mm)
            r[mm] = *(const float4*)(gp + (size_t)mm * MSTR);
    };
    // LDS layout per buffer: [nn][ol 0..31][k 0..63] bf16, addr ^= (ol&7)<<4.
    auto stage_write = [&](int c, const float4* r) {
        unsigned base = (unsigned)(c % 3) * 32768u;
        #pragma unroll
        for (int j = 0; j < 4; ++j) {
            int nn = half * 4 + j;
            bf16x8 v;
            #pragma unroll
            for (int mm = 0; mm < 8; ++mm)
                v[mm] = (__bf16)(((const float*)&r[mm])[j]);
            unsigned addr = (unsigned)(nn * 4096 + ol * 128 + mseg * 16);
            addr ^= (unsigned)((ol & 7) << 4);
            *(bf16x8*)(wlds + base + addr) = v;
        }
    };

    // ---- Prologue ----
    float4 srA[8], srB[8];
    stage_issue(0, srA);                 // oldest in vm queue -> drains first

    // x fragments (A operand): full 64 b-rows for this wave's neuron
    float4 xr[2][4][2];
    #pragma unroll
    for (int kc = 0; kc < 2; ++kc)
        #pragma unroll
        for (int bt = 0; bt < 4; ++bt) {
            int b = bt * 16 + col;
            const float* xp = x + ((size_t)b * N_TOT + n) * M_DIM + kc * 32 + kg * 8;
            xr[kc][bt][0] = *(const float4*)xp;
            xr[kc][bt][1] = *(const float4*)(xp + 4);
        }
    float bv[8];
    #pragma unroll
    for (int ot = 0; ot < 8; ++ot)
        bv[ot] = b1[(size_t)n * O_DIM + ot * 16 + col];

    stage_issue(1, srB);                 // chunk 1 into flight behind x

    stage_write(0, srA);                 // waits only chunk-0 loads

    bf16x8 af[2][4];                     // convert x while writes drain
    #pragma unroll
    for (int kc = 0; kc < 2; ++kc)
        #pragma unroll
        for (int bt = 0; bt < 4; ++bt) {
            const float* lp = (const float*)&xr[kc][bt][0];
            const float* hp = (const float*)&xr[kc][bt][1];
            bf16x8 v;
            #pragma unroll
            for (int j = 0; j < 4; ++j) {
                v[j]     = (__bf16)lp[j];
                v[4 + j] = (__bf16)hp[j];
            }
            af[kc][bt] = v;
        }

    asm volatile("s_waitcnt lgkmcnt(0)" ::: "memory");
    __builtin_amdgcn_s_barrier();
    __builtin_amdgcn_sched_barrier(0);

    // ---- Main loop: 4 chunks of 32 o-columns ----
    const unsigned sw = (unsigned)(col & 7) << 4;
    #pragma unroll
    for (int c = 0; c < 4; ++c) {
        if (c < 2) stage_issue(c + 2, (c & 1) ? srB : srA);  // 1 iter ahead

        // compute chunk c: 4 ds_read_b128 + 16 MFMAs
        unsigned base = (unsigned)(c % 3) * 32768u;
        f32x4 acc[4][2];
        #pragma unroll
        for (int otl = 0; otl < 2; ++otl) {
            // logical addr first (bit 6 clean: kg*16 <= 48), swizzle LAST
            unsigned la = (unsigned)(wave * 4096 + otl * 2048 + col * 128 + kg * 16);
            bf16x8 bf0 = *(const bf16x8*)(wlds + base + (la ^ sw));         // k 0..31
            bf16x8 bf1 = *(const bf16x8*)(wlds + base + ((la + 64) ^ sw));  // k 32..63
            f32x4 ci;
            float b0 = bv[c * 2 + otl];
            ci[0] = b0; ci[1] = b0; ci[2] = b0; ci[3] = b0;
            #pragma unroll
            for (int bt = 0; bt < 4; ++bt) {
                acc[bt][otl] = __builtin_amdgcn_mfma_f32_16x16x32_bf16(af[0][bt], bf0, ci,           0, 0, 0);
                acc[bt][otl] = __builtin_amdgcn_mfma_f32_16x16x32_bf16(af[1][bt], bf1, acc[bt][otl], 0, 0, 0);
            }
        }

        // ds_write chunk c+1 (its loads were issued one full iteration ago)
        if (c < 3) stage_write(c + 1, (c & 1) ? srA : srB);

        // store chunk c: both 64 B halves of each (b,n)-row's 128 B region
        // back-to-back -> clean write-back
        #pragma unroll
        for (int bt = 0; bt < 4; ++bt)
            #pragma unroll
            for (int r = 0; r < 4; ++r) {
                int b = bt * 16 + kg * 4 + r;
                float* op = out + ((size_t)b * N_TOT + n) * O_DIM + c * 32 + col;
                op[0]  = acc[bt][0][r];
                op[16] = acc[bt][1][r];
            }

        if (c < 3) {
            asm volatile("s_waitcnt lgkmcnt(0)" ::: "memory");
            __builtin_amdgcn_s_barrier();
            __builtin_amdgcn_sched_barrier(0);
        }
    }
}

extern "C" void kernel_launch(void* const* d_in, const int* in_sizes, int n_in,
                              void* d_out, int out_size, void* d_ws, size_t ws_size,
                              hipStream_t stream) {
    const float* x  = (const float*)d_in[0];
    const float* w1 = (const float*)d_in[1];
    const float* b1 = (const float*)d_in[2];
    float* out = (float*)d_out;
    superlinear_mfma<<<dim3(256), dim3(512), 0, stream>>>(x, w1, b1, out);
}